// Round 3
// baseline (1378.075 us; speedup 1.0000x reference)
//
#include <hip/hip_runtime.h>

#define TOK   8192
#define DD    1024
#define FF    4096
#define EE    8
#define TWOF  8192
#define NSLOT 16384   // TOK * top_k(2)

typedef unsigned short u16;
typedef float  f32x4  __attribute__((ext_vector_type(4)));
typedef __bf16 bf16x8 __attribute__((ext_vector_type(8)));

__device__ __forceinline__ u16 f2b(float f) {
  unsigned u = __builtin_bit_cast(unsigned, f);
  u += 0x7fffu + ((u >> 16) & 1u);   // RNE; inputs finite
  return (u16)(u >> 16);
}

__device__ __forceinline__ void ldslds16(const void* g, void* l) {
  __builtin_amdgcn_global_load_lds((const __attribute__((address_space(1))) void*)g,
                                   (__attribute__((address_space(3))) void*)l, 16, 0, 0);
}

__device__ __forceinline__ int imin(int a, int b) { return a < b ? a : b; }

// ---------------- gate: logits, softmax, top-2, counts ----------------
__global__ void gate_kernel(const float* __restrict__ x, const float* __restrict__ gw,
                            const float* __restrict__ gb, int* __restrict__ counts,
                            int* __restrict__ eidx, int* __restrict__ epos,
                            float* __restrict__ ew) {
  const int wave = threadIdx.x >> 6, lane = threadIdx.x & 63;
  const int t = blockIdx.x * 4 + wave;
  float acc[EE] = {0,0,0,0,0,0,0,0};
  const float* xr = x + (size_t)t * DD;
  for (int d = lane; d < DD; d += 64) {
    float xv = xr[d];
    const float* g = gw + (size_t)d * EE;
#pragma unroll
    for (int e = 0; e < EE; ++e) acc[e] += xv * g[e];
  }
#pragma unroll
  for (int e = 0; e < EE; ++e)
#pragma unroll
    for (int off = 32; off > 0; off >>= 1) acc[e] += __shfl_down(acc[e], off);
  if (lane == 0) {
    float l[EE];
#pragma unroll
    for (int e = 0; e < EE; ++e) l[e] = acc[e] + gb[e];
    int i0 = 0;
    for (int e = 1; e < EE; ++e) if (l[e] > l[i0]) i0 = e;
    int i1 = (i0 == 0) ? 1 : 0;
    for (int e = 0; e < EE; ++e) { if (e == i0) continue; if (l[e] > l[i1]) i1 = e; }
    float m = l[0];
    for (int e = 1; e < EE; ++e) m = fmaxf(m, l[e]);
    float s = 0.f, p[EE];
    for (int e = 0; e < EE; ++e) { p[e] = __expf(l[e] - m); s += p[e]; }
    float w0 = p[i0] / s, w1 = p[i1] / s;
    int p0 = atomicAdd(&counts[i0], 1);
    int p1 = atomicAdd(&counts[i1], 1);
    eidx[2*t] = i0; eidx[2*t+1] = i1;
    epos[2*t] = p0; epos[2*t+1] = p1;
    ew[2*t] = w0;  ew[2*t+1] = w1;
  }
}

__global__ void scan_kernel(const int* __restrict__ counts, int* __restrict__ offs) {
  if (threadIdx.x == 0 && blockIdx.x == 0) {
    int s = 0;
    for (int e = 0; e < EE; ++e) { offs[e] = s; s += counts[e]; }
    offs[EE] = s;
  }
}

__global__ void slot_kernel(const int* __restrict__ eidx, const int* __restrict__ epos,
                            const float* __restrict__ ew, const int* __restrict__ offs,
                            int* __restrict__ s2t, float* __restrict__ swt,
                            int* __restrict__ t2s) {
  int i = blockIdx.x * 256 + threadIdx.x;           // 0..2T-1
  int e = eidx[i];
  int slot = offs[e] + epos[i];
  s2t[slot] = i >> 1;
  swt[slot] = ew[i];
  t2s[i] = slot;
}

// ---------------- conversions ----------------
__global__ void cvtx_kernel(const float* __restrict__ x, u16* __restrict__ xb) {
  int i = blockIdx.x * 256 + threadIdx.x;           // 4 elements each
  float4 v = ((const float4*)x)[i];
  unsigned lo = (unsigned)f2b(v.x) | ((unsigned)f2b(v.y) << 16);
  unsigned hi = (unsigned)f2b(v.z) | ((unsigned)f2b(v.w) << 16);
  ((uint2*)xb)[i] = make_uint2(lo, hi);
}

__global__ void gather_kernel(const u16* __restrict__ xb, const int* __restrict__ s2t,
                              u16* __restrict__ xg) {
  int i = blockIdx.x * 256 + threadIdx.x;           // 16B chunks
  int row = i >> 7, c = i & 127;
  int tok = s2t[row];
  ((int4*)xg)[(size_t)row * 128 + c] = ((const int4*)xb)[(size_t)tok * 128 + c];
}

// transpose-convert weights: dst[seg][n][k] (bf16) = src[seg][k][oc(n)] (f32)
__global__ void wt_kernel(const float* __restrict__ srcS, const float* __restrict__ srcR,
                          u16* __restrict__ dst, int K, int N, int permute) {
  __shared__ float tile[32][33];
  const int seg = blockIdx.z;
  const float* src = (seg == 0) ? srcS : srcR + (size_t)(seg - 1) * K * N;
  const int pc0 = blockIdx.x * 32, k0 = blockIdx.y * 32;
  const int tid = threadIdx.x;
  {
    int kk = tid >> 3, j4 = (tid & 7) << 2;
    const float* srow = src + (size_t)(k0 + kk) * N;
#pragma unroll
    for (int q = 0; q < 4; ++q) {
      int n = pc0 + j4 + q;
      int oc = permute ? (((n >> 5) << 4) + (n & 15) + ((n & 16) ? FF : 0)) : n;
      tile[kk][j4 + q] = srow[oc];
    }
  }
  __syncthreads();
  {
    int pp = tid >> 3, kq = (tid & 7) << 2;
    u16* drow = dst + (size_t)seg * N * K + (size_t)(pc0 + pp) * K + k0 + kq;
#pragma unroll
    for (int q = 0; q < 4; ++q) drow[q] = f2b(tile[kq + q][pp]);
  }
}

// ================= 128x128x64 GEMM core (single-buffered, swizzled) =================
// 4 waves (2Mx2N), per-wave 64x64 out. LDS 32 KiB -> 4-5 blocks/CU.
// Swizzle: byte col ^= (row&7)<<4 on 128B rows; applied to gload source AND ds_read.

__device__ __forceinline__ bf16x8 ldf(const u16* buf, int row, int kbyte) {
  return *(const bf16x8*)((const char*)buf + row * 128 + (kbyte ^ ((row & 7) << 4)));
}

__device__ __forceinline__ void kloop(int niter,
    const char* a0, const char* a1, const char* a2, const char* a3,
    const char* b0, const char* b1, const char* b2, const char* b3,
    u16* As, u16* Bs, int tid, int lane, int wm, int wn, f32x4 (&acc)[4][4]) {
  const int fr = lane & 15, g16 = (lane >> 4) * 16;   // bytes
  for (int it = 0; it < niter; ++it) {
    const long long kb = (long long)it * 128;          // 64 u16 per iter
    ldslds16(a0 + kb, As + tid * 8);
    ldslds16(a1 + kb, As + 2048 + tid * 8);
    ldslds16(a2 + kb, As + 4096 + tid * 8);
    ldslds16(a3 + kb, As + 6144 + tid * 8);
    ldslds16(b0 + kb, Bs + tid * 8);
    ldslds16(b1 + kb, Bs + 2048 + tid * 8);
    ldslds16(b2 + kb, Bs + 4096 + tid * 8);
    ldslds16(b3 + kb, Bs + 6144 + tid * 8);
    __syncthreads();
    bf16x8 af[4], bq[4];
#pragma unroll
    for (int ks = 0; ks < 2; ++ks) {
      const int kbb = ks * 64 + g16;
#pragma unroll
      for (int mi = 0; mi < 4; ++mi) af[mi] = ldf(As, wm*64 + mi*16 + fr, kbb);
#pragma unroll
      for (int ni = 0; ni < 4; ++ni) bq[ni] = ldf(Bs, wn*64 + ni*16 + fr, kbb);
#pragma unroll
      for (int mi = 0; mi < 4; ++mi)
#pragma unroll
        for (int ni = 0; ni < 4; ++ni)
          acc[mi][ni] = __builtin_amdgcn_mfma_f32_16x16x32_bf16(af[mi], bq[ni], acc[mi][ni], 0, 0, 0);
    }
    __syncthreads();
  }
}

// ---------------- GEMM1: x @ w1t(permuted) -> SwiGLU -> hs bf16 ----------------
__global__ __launch_bounds__(256)
void gemm1_kernel(const u16* __restrict__ xb, const u16* __restrict__ xg,
                  const u16* __restrict__ w1t, const float* __restrict__ sb1,
                  const float* __restrict__ rb1, const int* __restrict__ offs,
                  u16* __restrict__ hs) {
  __shared__ __align__(16) u16 As[128 * 64];
  __shared__ __align__(16) u16 Bs[128 * 64];
  const int seg = blockIdx.z;
  int rowstart, rows, hsbase, atot;
  const u16* A;
  if (seg == 0) { A = xb; rowstart = 0; rows = TOK; hsbase = 0; atot = TOK; }
  else {
    int o0 = offs[seg - 1], o1 = offs[seg];
    A = xg; rowstart = o0; rows = o1 - o0; hsbase = TOK + o0; atot = NSLOT;
  }
  const int tm = blockIdx.y;
  if (tm * 128 >= rows) return;
  const int tn = blockIdx.x;
  const int tid = threadIdx.x, lane = tid & 63, wid = tid >> 6;
  const int wm = wid >> 1, wn = wid & 1;

  const int srow = tid >> 3;
  const int scol = ((tid & 7) * 16) ^ ((srow & 7) << 4);
  const char* Ac = (const char*)A;
  const char* Bc = (const char*)(w1t + (size_t)seg * TWOF * DD);
  const char* a[4]; const char* b[4];
#pragma unroll
  for (int r = 0; r < 4; ++r) {
    int rg = imin(rowstart + tm * 128 + r * 32 + srow, atot - 1);
    a[r] = Ac + (size_t)rg * (DD * 2) + scol;
    b[r] = Bc + (size_t)(tn * 128 + r * 32 + srow) * (DD * 2) + scol;
  }

  f32x4 acc[4][4] = {};
  kloop(DD / 64, a[0], a[1], a[2], a[3], b[0], b[1], b[2], b[3],
        As, Bs, tid, lane, wm, wn, acc);

  const int fr = lane & 15;
  const int rlim = rows - tm * 128;
  const int rb = wm * 64 + (lane >> 4) * 4;
  const float* b1 = (seg == 0) ? sb1 : rb1 + (size_t)(seg - 1) * TWOF;
  u16* hbase = hs + (size_t)(hsbase + tm * 128) * FF;
  const int fc = tn * 64 + wn * 32 + fr;
#pragma unroll
  for (int np = 0; np < 2; ++np) {
    const int f = fc + np * 16;
    const float ba = b1[f], bb = b1[FF + f];
#pragma unroll
    for (int m = 0; m < 4; ++m)
#pragma unroll
      for (int q = 0; q < 4; ++q) {
        int lr = rb + m * 16 + q;
        if (lr < rlim) {
          float av = acc[m][2*np][q] + ba;
          float bv = acc[m][2*np+1][q] + bb;
          float sv = av / (1.0f + __expf(-av)) * bv;
          hbase[(size_t)lr * FF + f] = f2b(sv);
        }
      }
  }
}

// ---------------- GEMM2: hs @ w2t -> yo (f32, all segments, no atomics) ----------------
__global__ __launch_bounds__(256)
void gemm2_kernel(const u16* __restrict__ hs, const u16* __restrict__ w2t,
                  const float* __restrict__ sb2, const float* __restrict__ rb2,
                  const int* __restrict__ offs, float* __restrict__ yo) {
  __shared__ __align__(16) u16 As[128 * 64];
  __shared__ __align__(16) u16 Bs[128 * 64];
  const int seg = blockIdx.z;
  int rows, hrow0;
  if (seg == 0) { rows = TOK; hrow0 = 0; }
  else {
    int o0 = offs[seg - 1], o1 = offs[seg];
    rows = o1 - o0; hrow0 = TOK + o0;
  }
  const int tm = blockIdx.y;
  if (tm * 128 >= rows) return;
  const int tn = blockIdx.x;
  const int tid = threadIdx.x, lane = tid & 63, wid = tid >> 6;
  const int wm = wid >> 1, wn = wid & 1;

  const int srow = tid >> 3;
  const int scol = ((tid & 7) * 16) ^ ((srow & 7) << 4);
  const char* Ac = (const char*)hs;
  const char* Bc = (const char*)(w2t + (size_t)seg * DD * FF);
  const char* a[4]; const char* b[4];
#pragma unroll
  for (int r = 0; r < 4; ++r) {
    a[r] = Ac + (size_t)(hrow0 + tm * 128 + r * 32 + srow) * (FF * 2) + scol;
    b[r] = Bc + (size_t)(tn * 128 + r * 32 + srow) * (FF * 2) + scol;
  }

  f32x4 acc[4][4] = {};
  kloop(FF / 64, a[0], a[1], a[2], a[3], b[0], b[1], b[2], b[3],
        As, Bs, tid, lane, wm, wn, acc);

  const int fr = lane & 15;
  const int rlim = rows - tm * 128;
  const int rb = wm * 64 + (lane >> 4) * 4;
  const float* b2 = (seg == 0) ? sb2 : rb2 + (size_t)(seg - 1) * DD;
  const int cc = tn * 128 + wn * 64 + fr;
  float bias[4];
#pragma unroll
  for (int n = 0; n < 4; ++n) bias[n] = b2[cc + n * 16];
  float* ybase = yo + (size_t)(hrow0 + tm * 128) * DD;
#pragma unroll
  for (int m = 0; m < 4; ++m)
#pragma unroll
    for (int q = 0; q < 4; ++q) {
      int lr = rb + m * 16 + q;
      if (lr >= rlim) continue;
      float* orow = ybase + (size_t)lr * DD;
#pragma unroll
      for (int n = 0; n < 4; ++n) orow[cc + n * 16] = acc[m][n][q] + bias[n];
    }
}

// ---------------- combine: out[t] = yo[t] + w0*yo[T+s0] + w1*yo[T+s1] ----------------
__global__ void combine_kernel(const float* __restrict__ yo, const int* __restrict__ t2s,
                               const float* __restrict__ ew, float* __restrict__ out) {
  const int t = blockIdx.x, d = threadIdx.x;   // 256 threads x 4 floats
  const float4 a  = ((const float4*)(yo + (size_t)t * DD))[d];
  const int s0 = t2s[2*t], s1 = t2s[2*t+1];
  const float w0 = ew[2*t], w1 = ew[2*t+1];
  const float4 r0 = ((const float4*)(yo + (size_t)(TOK + s0) * DD))[d];
  const float4 r1 = ((const float4*)(yo + (size_t)(TOK + s1) * DD))[d];
  float4 r;
  r.x = a.x + w0 * r0.x + w1 * r1.x;
  r.y = a.y + w0 * r0.y + w1 * r1.y;
  r.z = a.z + w0 * r0.z + w1 * r1.z;
  r.w = a.w + w0 * r0.w + w1 * r1.w;
  ((float4*)(out + (size_t)t * DD))[d] = r;
}

// ---------------- launch ----------------
extern "C" void kernel_launch(void* const* d_in, const int* in_sizes, int n_in,
                              void* d_out, int out_size, void* d_ws, size_t ws_size,
                              hipStream_t stream) {
  const float* x   = (const float*)d_in[0];
  const float* gw  = (const float*)d_in[1];
  const float* gb  = (const float*)d_in[2];
  const float* sw1 = (const float*)d_in[3];
  const float* sb1 = (const float*)d_in[4];
  const float* sw2 = (const float*)d_in[5];
  const float* sb2 = (const float*)d_in[6];
  const float* rw1 = (const float*)d_in[7];
  const float* rb1 = (const float*)d_in[8];
  const float* rw2 = (const float*)d_in[9];
  const float* rb2 = (const float*)d_in[10];
  float* out = (float*)d_out;

  char* p = (char*)d_ws;
  auto alloc = [&](size_t bytes) { char* r = p; p += (bytes + 255) & ~(size_t)255; return r; };
  int*   counts = (int*)alloc(EE * 4);
  int*   offs   = (int*)alloc((EE + 1) * 4);
  int*   eidx   = (int*)alloc((size_t)2 * TOK * 4);
  int*   epos   = (int*)alloc((size_t)2 * TOK * 4);
  float* ew     = (float*)alloc((size_t)2 * TOK * 4);
  int*   s2t    = (int*)alloc((size_t)NSLOT * 4);
  float* swt    = (float*)alloc((size_t)NSLOT * 4);
  int*   t2s    = (int*)alloc((size_t)2 * TOK * 4);
  u16*   xb     = (u16*)alloc((size_t)TOK * DD * 2);
  u16*   xg     = (u16*)alloc((size_t)NSLOT * DD * 2);
  u16*   w1t    = (u16*)alloc((size_t)9 * TWOF * DD * 2);
  u16*   w2t    = (u16*)alloc((size_t)9 * DD * FF * 2);
  u16*   hs     = (u16*)alloc((size_t)(TOK + NSLOT + 256) * FF * 2);
  // yo aliases w1t: gemm2 runs strictly after gemm1 (same stream); ~100.8MB <= 151MB
  float* yo     = (float*)w1t;

  hipMemsetAsync(counts, 0, EE * 4, stream);
  gate_kernel<<<TOK / 4, 256, 0, stream>>>(x, gw, gb, counts, eidx, epos, ew);
  scan_kernel<<<1, 64, 0, stream>>>(counts, offs);
  slot_kernel<<<(2 * TOK) / 256, 256, 0, stream>>>(eidx, epos, ew, offs, s2t, swt, t2s);
  cvtx_kernel<<<(TOK * DD / 4) / 256, 256, 0, stream>>>(x, xb);
  gather_kernel<<<(NSLOT * 128) / 256, 256, 0, stream>>>(xb, s2t, xg);
  wt_kernel<<<dim3(TWOF / 32, DD / 32, 9), 256, 0, stream>>>(sw1, rw1, w1t, DD, TWOF, 1);
  wt_kernel<<<dim3(DD / 32, FF / 32, 9), 256, 0, stream>>>(sw2, rw2, w2t, FF, DD, 0);
  gemm1_kernel<<<dim3(TWOF / 128, 64, 9), 256, 0, stream>>>(xb, xg, w1t, sb1, rb1, offs, hs);
  gemm2_kernel<<<dim3(DD / 128, 192, 9), 256, 0, stream>>>(hs, w2t, sb2, rb2, offs, yo);
  combine_kernel<<<TOK, 256, 0, stream>>>(yo, t2s, ew, out);
}

// Round 4
// 1145.670 us; speedup vs baseline: 1.2029x; 1.2029x over previous
//
#include <hip/hip_runtime.h>

#define TOK   8192
#define DD    1024
#define FF    4096
#define EE    8
#define TWOF  8192
#define NSLOT 16384   // TOK * top_k(2)

typedef unsigned short u16;
typedef float  f32x16 __attribute__((ext_vector_type(16)));
typedef __bf16 bf16x8 __attribute__((ext_vector_type(8)));

__device__ __forceinline__ u16 f2b(float f) {
  unsigned u = __builtin_bit_cast(unsigned, f);
  u += 0x7fffu + ((u >> 16) & 1u);   // RNE; inputs finite
  return (u16)(u >> 16);
}

__device__ __forceinline__ void ldslds16(const void* g, void* l) {
  __builtin_amdgcn_global_load_lds((const __attribute__((address_space(1))) void*)g,
                                   (__attribute__((address_space(3))) void*)l, 16, 0, 0);
}

__device__ __forceinline__ int imin(int a, int b) { return a < b ? a : b; }

// ---------------- gate: logits, softmax, top-2, counts ----------------
__global__ void gate_kernel(const float* __restrict__ x, const float* __restrict__ gw,
                            const float* __restrict__ gb, int* __restrict__ counts,
                            int* __restrict__ eidx, int* __restrict__ epos,
                            float* __restrict__ ew) {
  const int wave = threadIdx.x >> 6, lane = threadIdx.x & 63;
  const int t = blockIdx.x * 4 + wave;
  float acc[EE] = {0,0,0,0,0,0,0,0};
  const float* xr = x + (size_t)t * DD;
  for (int d = lane; d < DD; d += 64) {
    float xv = xr[d];
    const float* g = gw + (size_t)d * EE;
#pragma unroll
    for (int e = 0; e < EE; ++e) acc[e] += xv * g[e];
  }
#pragma unroll
  for (int e = 0; e < EE; ++e)
#pragma unroll
    for (int off = 32; off > 0; off >>= 1) acc[e] += __shfl_down(acc[e], off);
  if (lane == 0) {
    float l[EE];
#pragma unroll
    for (int e = 0; e < EE; ++e) l[e] = acc[e] + gb[e];
    int i0 = 0;
    for (int e = 1; e < EE; ++e) if (l[e] > l[i0]) i0 = e;
    int i1 = (i0 == 0) ? 1 : 0;
    for (int e = 0; e < EE; ++e) { if (e == i0) continue; if (l[e] > l[i1]) i1 = e; }
    float m = l[0];
    for (int e = 1; e < EE; ++e) m = fmaxf(m, l[e]);
    float s = 0.f, p[EE];
    for (int e = 0; e < EE; ++e) { p[e] = __expf(l[e] - m); s += p[e]; }
    float w0 = p[i0] / s, w1 = p[i1] / s;
    int p0 = atomicAdd(&counts[i0], 1);
    int p1 = atomicAdd(&counts[i1], 1);
    eidx[2*t] = i0; eidx[2*t+1] = i1;
    epos[2*t] = p0; epos[2*t+1] = p1;
    ew[2*t] = w0;  ew[2*t+1] = w1;
  }
}

// slot: inline-scans counts (8 ints, L2-hot) — no separate scan kernel
__global__ void slot_kernel(const int* __restrict__ eidx, const int* __restrict__ epos,
                            const float* __restrict__ ew, const int* __restrict__ counts,
                            int* __restrict__ s2t, float* __restrict__ swt,
                            int* __restrict__ t2s) {
  int i = blockIdx.x * 256 + threadIdx.x;           // 0..2T-1
  int e = eidx[i];
  int off = 0;
  for (int j = 0; j < e; ++j) off += counts[j];
  int slot = off + epos[i];
  s2t[slot] = i >> 1;
  swt[slot] = ew[i];
  t2s[i] = slot;
}

// ---------------- conversions ----------------
__global__ void cvtx_kernel(const float* __restrict__ x, u16* __restrict__ xb) {
  int i = blockIdx.x * 256 + threadIdx.x;           // 4 elements each
  float4 v = ((const float4*)x)[i];
  unsigned lo = (unsigned)f2b(v.x) | ((unsigned)f2b(v.y) << 16);
  unsigned hi = (unsigned)f2b(v.z) | ((unsigned)f2b(v.w) << 16);
  ((uint2*)xb)[i] = make_uint2(lo, hi);
}

__global__ void gather_kernel(const u16* __restrict__ xb, const int* __restrict__ s2t,
                              u16* __restrict__ xg) {
  int i = blockIdx.x * 256 + threadIdx.x;           // 16B chunks
  int row = i >> 7, c = i & 127;
  int tok = s2t[row];
  ((int4*)xg)[(size_t)row * 128 + c] = ((const int4*)xb)[(size_t)tok * 128 + c];
}

// transpose-convert weights: dst[seg][n][k] (bf16) = src[seg][k][oc(n)] (f32)
// permute (w1 only): interleave a/b halves in 32-col groups (SwiGLU pairing, 32x32 MFMA)
__global__ void wt_kernel(const float* __restrict__ srcS, const float* __restrict__ srcR,
                          u16* __restrict__ dst, int K, int N, int permute) {
  __shared__ float tile[32][33];
  const int seg = blockIdx.z;
  const float* src = (seg == 0) ? srcS : srcR + (size_t)(seg - 1) * K * N;
  const int pc0 = blockIdx.x * 32, k0 = blockIdx.y * 32;
  const int tid = threadIdx.x;
  {
    int kk = tid >> 3, j4 = (tid & 7) << 2;
    const float* srow = src + (size_t)(k0 + kk) * N;
#pragma unroll
    for (int q = 0; q < 4; ++q) {
      int n = pc0 + j4 + q;
      int oc = permute ? (((n >> 6) << 5) + (n & 31) + ((n & 32) ? FF : 0)) : n;
      tile[kk][j4 + q] = srow[oc];
    }
  }
  __syncthreads();
  {
    int pp = tid >> 3, kq = (tid & 7) << 2;
    u16* drow = dst + (size_t)seg * N * K + (size_t)(pc0 + pp) * K + k0 + kq;
#pragma unroll
    for (int q = 0; q < 4; ++q) drow[q] = f2b(tile[kq + q][pp]);
  }
}

// ================= 128x128x64 GEMM core — 32x32x16 MFMA, hoisted swizzled bases =====
// 4 waves (2Mx2N), per-wave 64x64 out (2x2 frags of 32x32). LDS 32 KiB.
// Swizzle: byte col ^= (row&7)<<4 on 128B rows; pre-swizzled global source + swizzled read.

__device__ __forceinline__ void kloop32(int niter,
    const char* a0, const char* a1, const char* a2, const char* a3,
    const char* b0, const char* b1, const char* b2, const char* b3,
    u16* As, u16* Bs, int tid, f32x16 (&acc)[2][2]) {
  const int lane = tid & 63, l31 = lane & 31, kg = (lane >> 5) * 16;
  const int wid = tid >> 6, wm = wid >> 1, wn = wid & 1;
  const int C = (l31 & 7) << 4;
  const char* rA[4]; const char* rB[4];
#pragma unroll
  for (int ks = 0; ks < 4; ++ks) {        // 4 k-windows of 16 within BK=64
    const int o = (ks * 32 + kg) ^ C;
    rA[ks] = (const char*)As + (wm * 64 + l31) * 128 + o;
    rB[ks] = (const char*)Bs + (wn * 64 + l31) * 128 + o;
  }
  for (int it = 0; it < niter; ++it) {
    const long long kb = (long long)it * 128;        // 64 u16 per iter
    ldslds16(a0 + kb, As + tid * 8);
    ldslds16(a1 + kb, As + 2048 + tid * 8);
    ldslds16(a2 + kb, As + 4096 + tid * 8);
    ldslds16(a3 + kb, As + 6144 + tid * 8);
    ldslds16(b0 + kb, Bs + tid * 8);
    ldslds16(b1 + kb, Bs + 2048 + tid * 8);
    ldslds16(b2 + kb, Bs + 4096 + tid * 8);
    ldslds16(b3 + kb, Bs + 6144 + tid * 8);
    __syncthreads();
#pragma unroll
    for (int ks = 0; ks < 4; ++ks) {
      bf16x8 af0 = *(const bf16x8*)(rA[ks]);
      bf16x8 af1 = *(const bf16x8*)(rA[ks] + 4096);   // +32 rows
      bf16x8 bq0 = *(const bf16x8*)(rB[ks]);
      bf16x8 bq1 = *(const bf16x8*)(rB[ks] + 4096);
      acc[0][0] = __builtin_amdgcn_mfma_f32_32x32x16_bf16(af0, bq0, acc[0][0], 0, 0, 0);
      acc[0][1] = __builtin_amdgcn_mfma_f32_32x32x16_bf16(af0, bq1, acc[0][1], 0, 0, 0);
      acc[1][0] = __builtin_amdgcn_mfma_f32_32x32x16_bf16(af1, bq0, acc[1][0], 0, 0, 0);
      acc[1][1] = __builtin_amdgcn_mfma_f32_32x32x16_bf16(af1, bq1, acc[1][1], 0, 0, 0);
    }
    __syncthreads();
  }
}

// ---------------- GEMM1: x @ w1t(permuted) -> SwiGLU -> hs bf16 ----------------
__global__ __launch_bounds__(256, 4)
void gemm1_kernel(const u16* __restrict__ xb, const u16* __restrict__ xg,
                  const u16* __restrict__ w1t, const float* __restrict__ sb1,
                  const float* __restrict__ rb1, const int* __restrict__ counts,
                  u16* __restrict__ hs) {
  __shared__ __align__(16) u16 As[128 * 64];
  __shared__ __align__(16) u16 Bs[128 * 64];
  const int seg = blockIdx.z;
  int rowstart, rows, hsbase, atot;
  const u16* A;
  if (seg == 0) { A = xb; rowstart = 0; rows = TOK; hsbase = 0; atot = TOK; }
  else {
    int o0 = 0;
    for (int j = 0; j < seg - 1; ++j) o0 += counts[j];
    A = xg; rowstart = o0; rows = counts[seg - 1]; hsbase = TOK + o0; atot = NSLOT;
  }
  const int tm = blockIdx.y;
  if (tm * 128 >= rows) return;
  const int tn = blockIdx.x;
  const int tid = threadIdx.x, lane = tid & 63, wid = tid >> 6;
  const int wm = wid >> 1, wn = wid & 1;

  const int srow = tid >> 3;
  const int scol = ((tid & 7) * 16) ^ ((srow & 7) << 4);
  const char* Ac = (const char*)A;
  const char* Bc = (const char*)(w1t + (size_t)seg * TWOF * DD);
  const char* a[4]; const char* b[4];
#pragma unroll
  for (int r = 0; r < 4; ++r) {
    int rg = imin(rowstart + tm * 128 + r * 32 + srow, atot - 1);
    a[r] = Ac + (size_t)rg * (DD * 2) + scol;
    b[r] = Bc + (size_t)(tn * 128 + r * 32 + srow) * (DD * 2) + scol;
  }

  f32x16 acc[2][2] = {};
  kloop32(DD / 64, a[0], a[1], a[2], a[3], b[0], b[1], b[2], b[3],
          As, Bs, tid, acc);

  const int l31 = lane & 31, lg = lane >> 5;
  const int rlim = rows - tm * 128;
  const float* b1 = (seg == 0) ? sb1 : rb1 + (size_t)(seg - 1) * TWOF;
  const int f = (tn * 2 + wn) * 32 + l31;
  const float ba = b1[f], bb = b1[FF + f];
  u16* hbase = hs + (size_t)(hsbase + tm * 128) * FF;
#pragma unroll
  for (int mi = 0; mi < 2; ++mi)
#pragma unroll
    for (int reg = 0; reg < 16; ++reg) {
      int lr = wm * 64 + mi * 32 + (reg & 3) + 8 * (reg >> 2) + 4 * lg;
      if (lr < rlim) {
        float av = acc[mi][0][reg] + ba;
        float bv = acc[mi][1][reg] + bb;
        float sv = av / (1.0f + __expf(-av)) * bv;
        hbase[(size_t)lr * FF + f] = f2b(sv);
      }
    }
}

// ---------------- GEMM2: hs @ w2t -> yo (f32, all segments, no atomics) ----------------
__global__ __launch_bounds__(256, 4)
void gemm2_kernel(const u16* __restrict__ hs, const u16* __restrict__ w2t,
                  const float* __restrict__ sb2, const float* __restrict__ rb2,
                  const int* __restrict__ counts, float* __restrict__ yo) {
  __shared__ __align__(16) u16 As[128 * 64];
  __shared__ __align__(16) u16 Bs[128 * 64];
  const int seg = blockIdx.z;
  int rows, hrow0;
  if (seg == 0) { rows = TOK; hrow0 = 0; }
  else {
    int o0 = 0;
    for (int j = 0; j < seg - 1; ++j) o0 += counts[j];
    rows = counts[seg - 1]; hrow0 = TOK + o0;
  }
  const int tm = blockIdx.y;
  if (tm * 128 >= rows) return;
  const int tn = blockIdx.x;
  const int tid = threadIdx.x, lane = tid & 63, wid = tid >> 6;
  const int wm = wid >> 1, wn = wid & 1;

  const int srow = tid >> 3;
  const int scol = ((tid & 7) * 16) ^ ((srow & 7) << 4);
  const char* Ac = (const char*)hs;
  const char* Bc = (const char*)(w2t + (size_t)seg * DD * FF);
  const char* a[4]; const char* b[4];
#pragma unroll
  for (int r = 0; r < 4; ++r) {
    a[r] = Ac + (size_t)(hrow0 + tm * 128 + r * 32 + srow) * (FF * 2) + scol;
    b[r] = Bc + (size_t)(tn * 128 + r * 32 + srow) * (FF * 2) + scol;
  }

  f32x16 acc[2][2] = {};
  kloop32(FF / 64, a[0], a[1], a[2], a[3], b[0], b[1], b[2], b[3],
          As, Bs, tid, acc);

  const int l31 = lane & 31, lg = lane >> 5;
  const int rlim = rows - tm * 128;
  const float* b2 = (seg == 0) ? sb2 : rb2 + (size_t)(seg - 1) * DD;
  const int c0 = tn * 128 + wn * 64 + l31;
  const float bias0 = b2[c0], bias1 = b2[c0 + 32];
  float* ybase = yo + (size_t)(hrow0 + tm * 128) * DD;
#pragma unroll
  for (int mi = 0; mi < 2; ++mi)
#pragma unroll
    for (int reg = 0; reg < 16; ++reg) {
      int lr = wm * 64 + mi * 32 + (reg & 3) + 8 * (reg >> 2) + 4 * lg;
      if (lr < rlim) {
        float* orow = ybase + (size_t)lr * DD;
        orow[c0]      = acc[mi][0][reg] + bias0;
        orow[c0 + 32] = acc[mi][1][reg] + bias1;
      }
    }
}

// ---------------- combine: out[t] = yo[t] + w0*yo[T+s0] + w1*yo[T+s1] ----------------
__global__ void combine_kernel(const float* __restrict__ yo, const int* __restrict__ t2s,
                               const float* __restrict__ ew, float* __restrict__ out) {
  const int t = blockIdx.x, d = threadIdx.x;   // 256 threads x 4 floats
  const float4 a  = ((const float4*)(yo + (size_t)t * DD))[d];
  const int s0 = t2s[2*t], s1 = t2s[2*t+1];
  const float w0 = ew[2*t], w1 = ew[2*t+1];
  const float4 r0 = ((const float4*)(yo + (size_t)(TOK + s0) * DD))[d];
  const float4 r1 = ((const float4*)(yo + (size_t)(TOK + s1) * DD))[d];
  float4 r;
  r.x = a.x + w0 * r0.x + w1 * r1.x;
  r.y = a.y + w0 * r0.y + w1 * r1.y;
  r.z = a.z + w0 * r0.z + w1 * r1.z;
  r.w = a.w + w0 * r0.w + w1 * r1.w;
  ((float4*)(out + (size_t)t * DD))[d] = r;
}

// ---------------- launch ----------------
extern "C" void kernel_launch(void* const* d_in, const int* in_sizes, int n_in,
                              void* d_out, int out_size, void* d_ws, size_t ws_size,
                              hipStream_t stream) {
  const float* x   = (const float*)d_in[0];
  const float* gw  = (const float*)d_in[1];
  const float* gb  = (const float*)d_in[2];
  const float* sw1 = (const float*)d_in[3];
  const float* sb1 = (const float*)d_in[4];
  const float* sw2 = (const float*)d_in[5];
  const float* sb2 = (const float*)d_in[6];
  const float* rw1 = (const float*)d_in[7];
  const float* rb1 = (const float*)d_in[8];
  const float* rw2 = (const float*)d_in[9];
  const float* rb2 = (const float*)d_in[10];
  float* out = (float*)d_out;

  char* p = (char*)d_ws;
  auto alloc = [&](size_t bytes) { char* r = p; p += (bytes + 255) & ~(size_t)255; return r; };
  int*   counts = (int*)alloc(EE * 4);
  int*   eidx   = (int*)alloc((size_t)2 * TOK * 4);
  int*   epos   = (int*)alloc((size_t)2 * TOK * 4);
  float* ew     = (float*)alloc((size_t)2 * TOK * 4);
  int*   s2t    = (int*)alloc((size_t)NSLOT * 4);
  float* swt    = (float*)alloc((size_t)NSLOT * 4);
  int*   t2s    = (int*)alloc((size_t)2 * TOK * 4);
  u16*   xb     = (u16*)alloc((size_t)TOK * DD * 2);
  u16*   xg     = (u16*)alloc((size_t)NSLOT * DD * 2);
  u16*   w1t    = (u16*)alloc((size_t)9 * TWOF * DD * 2);
  u16*   w2t    = (u16*)alloc((size_t)9 * DD * FF * 2);
  u16*   hs     = (u16*)alloc((size_t)(TOK + NSLOT + 256) * FF * 2);
  // yo aliases w1t: gemm2 runs strictly after gemm1 (same stream); ~100.8MB <= 151MB
  float* yo     = (float*)w1t;

  hipMemsetAsync(counts, 0, EE * 4, stream);
  gate_kernel<<<TOK / 4, 256, 0, stream>>>(x, gw, gb, counts, eidx, epos, ew);
  slot_kernel<<<(2 * TOK) / 256, 256, 0, stream>>>(eidx, epos, ew, counts, s2t, swt, t2s);
  cvtx_kernel<<<(TOK * DD / 4) / 256, 256, 0, stream>>>(x, xb);
  gather_kernel<<<(NSLOT * 128) / 256, 256, 0, stream>>>(xb, s2t, xg);
  wt_kernel<<<dim3(TWOF / 32, DD / 32, 9), 256, 0, stream>>>(sw1, rw1, w1t, DD, TWOF, 1);
  wt_kernel<<<dim3(DD / 32, FF / 32, 9), 256, 0, stream>>>(sw2, rw2, w2t, FF, DD, 0);
  gemm1_kernel<<<dim3(TWOF / 128, 64, 9), 256, 0, stream>>>(xb, xg, w1t, sb1, rb1, counts, hs);
  gemm2_kernel<<<dim3(DD / 128, 64, 9), 256, 0, stream>>>(hs, w2t, sb2, rb2, counts, yo);
  combine_kernel<<<TOK, 256, 0, stream>>>(yo, t2s, ew, out);
}